// Round 5
// baseline (60.856 us; speedup 1.0000x reference)
//
#include <hip/hip_runtime.h>

// out[o,k,h,m] = sum_{i,j} p[o,i,(h-1)%14, m+j] * w[i,k,j]
// p[q]=0 for q in {0,15}; p[q]=x[o,i,n,(q-2)%14], n=(h-1)%14
//
// Grid (8,14,2)=224 blocks, block 512 = kk2(0..15) x s(0..31).
// Thread: i in [8s,8s+8), k in {kt*32+2kk2, +1}, all 14 m.
// R5 change: w (16 float3 loads) PREFETCHED into registers BEFORE xs staging,
// overlapping global-load latency with the staging phase; main loop is pure
// ds_read_b128 + FMA. Split-K partials via x17-padded LDS (aliased over xs).

#define BT 512

__global__ __launch_bounds__(BT) void shiftconv_kernel(
    const float* __restrict__ x,   // (2,256,14,14)
    const float* __restrict__ w,   // (256,256,3)
    float* __restrict__ out)       // (2,256,14,14)
{
    __shared__ __align__(16) float smem[32 * 28 * 17 + 2];  // 60936 B
    float* xs   = smem;        // phase 1: 256 padded rows x 16 floats
    float* part = smem;        // phase 2: split-K partials (aliased)

    const int kt = blockIdx.x;   // 0..7
    const int h  = blockIdx.y;   // 0..13
    const int o  = blockIdx.z;   // 0..1
    const int t  = threadIdx.x;  // 0..511
    const int n  = (h + 13) % 14;

    const int kk2 = t & 15;      // k-pair index
    const int s   = t >> 4;      // 0..31 split-K
    const int kg0 = kt * 32 + 2 * kk2;
    const int i0  = s * 8;

    // ---- prefetch w for this thread's (i-range, k-pair) into registers ----
    // Issued before staging so L2 latency overlaps the xs staging phase.
    float3 wA[8], wB[8];
    {
        const float* wp = w + ((size_t)i0 * 256 + kg0) * 3;  // stride 768/i
#pragma unroll
        for (int i = 0; i < 8; ++i) {
            wA[i] = *reinterpret_cast<const float3*>(wp);
            wB[i] = *reinterpret_cast<const float3*>(wp + 3);
            wp += 768;
        }
    }

    // ---- stage x[o,:,n,:] into padded LDS rows ----
    xs[(t >> 1) * 16 + (t & 1) * 15] = 0.0f;   // zeros at q=0,15
    for (int e = t; e < 256 * 14; e += BT) {
        int i  = e / 14;
        int ww = e - i * 14;
        float v = x[((size_t)(o * 256 + i) * 14 + n) * 14 + ww];
        xs[i * 16 + ((ww <= 12) ? (ww + 2) : 1)] = v;
    }
    __syncthreads();

    const float* xp = xs + i0 * 16;

    float accA[14], accB[14];
#pragma unroll
    for (int m = 0; m < 14; ++m) { accA[m] = 0.f; accB[m] = 0.f; }

#pragma unroll
    for (int i = 0; i < 8; ++i) {
        float4 q0 = *reinterpret_cast<const float4*>(xp);
        float4 q1 = *reinterpret_cast<const float4*>(xp + 4);
        float4 q2 = *reinterpret_cast<const float4*>(xp + 8);
        float4 q3 = *reinterpret_cast<const float4*>(xp + 12);
        float r[16] = {q0.x,q0.y,q0.z,q0.w, q1.x,q1.y,q1.z,q1.w,
                       q2.x,q2.y,q2.z,q2.w, q3.x,q3.y,q3.z,q3.w};
        float3 wa = wA[i];
        float3 wb = wB[i];
#pragma unroll
        for (int m = 0; m < 14; ++m) {
            accA[m] = fmaf(r[m],   wa.x, accA[m]);
            accA[m] = fmaf(r[m+1], wa.y, accA[m]);
            accA[m] = fmaf(r[m+2], wa.z, accA[m]);
            accB[m] = fmaf(r[m],   wb.x, accB[m]);
            accB[m] = fmaf(r[m+1], wb.y, accB[m]);
            accB[m] = fmaf(r[m+2], wb.z, accB[m]);
        }
        xp += 16;
    }

    __syncthreads();   // all xs reads done before part overwrites it

    // ---- write split-K partials: mu = u*14 + m ----
#pragma unroll
    for (int m = 0; m < 14; ++m) {
        part[(s * 28 + m)      * 17 + kk2] = accA[m];
        part[(s * 28 + 14 + m) * 17 + kk2] = accB[m];
    }
    __syncthreads();

    // ---- reduce over s, store ----
    if (t < 448) {
        int kk = t & 31;         // 0..31
        int m  = t >> 5;         // 0..13
        int k2 = kk >> 1;
        int mu = (kk & 1) * 14 + m;
        float sum = 0.f;
#pragma unroll
        for (int si = 0; si < 32; ++si)
            sum += part[(si * 28 + mu) * 17 + k2];
        out[((size_t)(o * 256 + kt * 32 + kk) * 14 + h) * 14 + m] = sum;
    }
}

extern "C" void kernel_launch(void* const* d_in, const int* in_sizes, int n_in,
                              void* d_out, int out_size, void* d_ws, size_t ws_size,
                              hipStream_t stream) {
    const float* x = (const float*)d_in[0];
    const float* w = (const float*)d_in[1];
    float* out = (float*)d_out;

    dim3 grid(8, 14, 2);
    dim3 block(BT);
    shiftconv_kernel<<<grid, block, 0, stream>>>(x, w, out);
}